// Round 2
// baseline (369.060 us; speedup 1.0000x reference)
//
#include <hip/hip_runtime.h>
#include <hip/hip_bf16.h>
#include <cstdint>
#include <cstddef>

// Problem constants
#define NTOK 32768   // P*N*K token-copies
#define FD   256     // input feature dim
#define HD   1024    // hidden dim
#define OD   256     // output dim
#define NEXP 8

// GEMM tiling (128-tile kernels: swiglu/gemm3)
#define BM 128
#define BN 128
#define BK 64
#define RT8 34       // ceil(max 128-row tiles (264+) / 8)
#define RT2_8 17     // ceil(max 256-row tiles (136) / 8) for the 8-phase kernel

typedef __bf16 bf16;
typedef __bf16 bf16x8 __attribute__((ext_vector_type(8)));
typedef __bf16 bf16x4 __attribute__((ext_vector_type(4)));
typedef float  f32x4  __attribute__((ext_vector_type(4)));
typedef int    i32x4  __attribute__((ext_vector_type(4)));

// async global->LDS, 16 B per lane. LDS dst MUST be wave-uniform base + lane*16.
__device__ __forceinline__ void cp16(const void* g, void* l) {
    __builtin_amdgcn_global_load_lds(
        (const __attribute__((address_space(1))) void*)g,
        (__attribute__((address_space(3))) void*)l, 16, 0, 0);
}

// inline-asm ds_read_b128 on a raw LDS byte address. Invisible to
// SIInsertWaitcnts -> no compiler-inserted vmcnt(0) against global_load_lds
// LDS-DMA writes (that auto-drain was Round-1's serializer). Ordering vs the
// DMA writes is carried by the barrier schedule + manual lgkmcnt/vmcnt.
__device__ __forceinline__ bf16x8 dsr128(uint32_t byteoff) {
    i32x4 r;
    asm volatile("ds_read_b128 %0, %1" : "=v"(r) : "v"(byteoff));
    return __builtin_bit_cast(bf16x8, r);
}

// ---- workspace layout (bytes) ----
static const size_t O_CNT  = 0;          // int[8]
static const size_t O_CUR  = 64;         // int[8]
static const size_t O_OFF  = 128;        // int[9]
static const size_t O_NT   = 192;        // int[1]
static const size_t O_NT2  = 196;        // int[1]  (256-row tile count)
static const size_t O_TE   = 1024;       // int[<=264 used]
static const size_t O_TE2  = 2112;       // int[<=136] (carved from O_TE tail)
static const size_t O_TR   = 3072;       // int[<=264 used]
static const size_t O_TR2  = 4160;       // int[<=136] (carved from O_TR tail)
static const size_t O_PERM = 5120;       // int[NTOK]
static const size_t O_XP   = 136192;     // bf16 [NTOK][FD]    (16 MB)
static const size_t O_WG   = 16913408;   // bf16 [E][HD][FD]   (4 MB)
static const size_t O_WU   = 21107712;   // bf16 [E][HD][FD]   (4 MB)
static const size_t O_W1   = 25302016;   // bf16 [E][HD][HD]   (16 MB)
static const size_t O_W2   = 42079232;   // bf16 [E][OD][HD]   (4 MB)
static const size_t O_H    = 46273536;   // bf16 [NTOK][HD]    (64 MB) Hbuf
static const size_t O_H2   = 113382400;  // bf16 [NTOK][HD]    (64 MB) H2

// ---------------- routing ----------------
__global__ void k_hist(const int* __restrict__ sel, int* __restrict__ cnt) {
    __shared__ int lcnt[NEXP];
    if (threadIdx.x < NEXP) lcnt[threadIdx.x] = 0;
    __syncthreads();
    int t = blockIdx.x * 256 + threadIdx.x;   // NTOK % 256 == 0
    atomicAdd(&lcnt[sel[t]], 1);
    __syncthreads();
    if (threadIdx.x < NEXP) atomicAdd(&cnt[threadIdx.x], lcnt[threadIdx.x]);
}

__global__ void k_plan(const int* __restrict__ cnt, int* __restrict__ off,
                       int* __restrict__ tileE, int* __restrict__ tileR,
                       int* __restrict__ nt,
                       int* __restrict__ tileE2, int* __restrict__ tileR2,
                       int* __restrict__ nt2) {
    if (threadIdx.x == 0 && blockIdx.x == 0) {
        int o = 0;
        for (int e = 0; e < NEXP; e++) { off[e] = o; o += cnt[e]; }
        off[NEXP] = o;
        int n = 0;
        for (int e = 0; e < NEXP; e++) {
            int c = cnt[e];
            int nte = (c + BM - 1) / BM;
            for (int r = 0; r < nte; r++) { tileE[n] = e; tileR[n] = r; n++; }
        }
        *nt = n;
        int n2 = 0;
        for (int e = 0; e < NEXP; e++) {
            int c = cnt[e];
            int nte = (c + 255) / 256;
            for (int r = 0; r < nte; r++) { tileE2[n2] = e; tileR2[n2] = r; n2++; }
        }
        *nt2 = n2;
    }
}

__global__ void k_scatter(const int* __restrict__ sel, const int* __restrict__ off,
                          int* __restrict__ cur, int* __restrict__ perm) {
    __shared__ int lcnt[NEXP];
    __shared__ int lbase[NEXP];
    if (threadIdx.x < NEXP) lcnt[threadIdx.x] = 0;
    __syncthreads();
    int t = blockIdx.x * 256 + threadIdx.x;
    int e = sel[t];
    int rank = atomicAdd(&lcnt[e], 1);
    __syncthreads();
    if (threadIdx.x < NEXP)
        lbase[threadIdx.x] = atomicAdd(&cur[threadIdx.x], lcnt[threadIdx.x]);
    __syncthreads();
    perm[off[e] + lbase[e] + rank] = t;
}

__global__ void k_gather(const float* __restrict__ x, const int* __restrict__ perm,
                         bf16* __restrict__ Xp) {
    int gid = blockIdx.x * 256 + threadIdx.x;
    int pos = gid >> 6;
    int c   = gid & 63;
    int tok = perm[pos];
    float4 v = ((const float4*)x)[(size_t)tok * 64 + c];
    bf16x4 o;
    o.x = (bf16)v.x; o.y = (bf16)v.y; o.z = (bf16)v.z; o.w = (bf16)v.w;
    *(bf16x4*)&Xp[(size_t)pos * FD + c * 4] = o;
}

// All 4 weight transposes in ONE launch. W [E][K][N] fp32 -> Wt [E][N][K] bf16.
#define TPE 448
__global__ void k_transpose_all(const float* __restrict__ Wg, bf16* __restrict__ Wgt,
                                const float* __restrict__ Wu, bf16* __restrict__ Wut,
                                const float* __restrict__ W1, bf16* __restrict__ W1t,
                                const float* __restrict__ W2, bf16* __restrict__ W2t) {
    __shared__ float tile[64][65];
    int b  = blockIdx.x;
    int e  = b / TPE;
    int tt = b % TPE;
    const float* Ws; bf16* Wd; int K, N;
    if (tt < 64)       { Ws = Wg; Wd = Wgt; K = FD; N = HD; }
    else if (tt < 128) { Ws = Wu; Wd = Wut; K = FD; N = HD; tt -= 64; }
    else if (tt < 384) { Ws = W1; Wd = W1t; K = HD; N = HD; tt -= 128; }
    else               { Ws = W2; Wd = W2t; K = HD; N = OD; tt -= 384; }
    int nk = K / 64;
    int k0 = (tt % nk) * 64, n0 = (tt / nk) * 64;
    Ws += (size_t)e * K * N;
    Wd += (size_t)e * K * N;
    int t = threadIdx.x;
    for (int q = 0; q < 4; q++) {
        int lin = t + q * 256;
        int r = lin >> 4, c4 = (lin & 15) * 4;
        float4 v = *(const float4*)&Ws[(size_t)(k0 + r) * N + n0 + c4];
        tile[r][c4] = v.x; tile[r][c4+1] = v.y; tile[r][c4+2] = v.z; tile[r][c4+3] = v.w;
    }
    __syncthreads();
    for (int q = 0; q < 2; q++) {   // 64 n * 8 chunks = 512 items
        int lin = t + q * 256;
        int n = lin >> 3, k8 = (lin & 7) * 8;
        bf16x8 o;
        for (int i = 0; i < 8; i++) o[i] = (bf16)tile[k8 + i][n];
        *(bf16x8*)&Wd[(size_t)(n0 + n) * K + k0 + k8] = o;
    }
}

// ---------------- GEMM kernels ----------------

#define DECODE_TILE(NTY, BNE)                                                  \
    int L = blockIdx.x;                                                        \
    int xcd = L & 7; int tq = L >> 3;                                          \
    int ny  = tq % (NTY); int Rhi = tq / (NTY);                                \
    int R   = Rhi * 8 + xcd;                                                   \
    if (R >= *ntp) return;                                                     \
    int e    = tileE[R];                                                       \
    int row0 = tileR[R] * BM;                                                  \
    int base = off[e];                                                         \
    int valid = off[e + 1] - base - row0; if (valid > BM) valid = BM;          \
    int n0 = ny * (BNE);                                                       \
    int tid = threadIdx.x;                                                     \
    int lane = tid & 63, wv = tid >> 6;                                        \
    int wm = wv & 1, wn = wv >> 1;                                             \
    int lr = lane & 15, qd = lane >> 4;

#define GEMM_KLOOP(KDIM)                                                       \
    for (int k0 = 0; k0 < (KDIM); k0 += BK) {                                  \
        for (int s = 0; s < 4; s++) {                                          \
            int ci = tid + s * 256;                                            \
            int row = ci >> 3;                                                 \
            int jg  = (ci & 7) ^ (row & 7);                                    \
            int mc  = row < valid ? row : valid - 1;                           \
            cp16(Ab + (size_t)mc  * (KDIM) + k0 + jg * 8, &As[ci * 8]);        \
            cp16(Bb + (size_t)row * (KDIM) + k0 + jg * 8, &Bs[ci * 8]);        \
        }                                                                      \
        __syncthreads();                                                       \
        for (int ks = 0; ks < 2; ks++) {                                       \
            bf16x8 af[4], bfr[4];                                              \
            for (int i = 0; i < 4; i++) {                                      \
                int row = wm * 64 + i * 16 + lr;                               \
                int sl  = (ks * 4 + qd) ^ (row & 7);                           \
                af[i] = *(const bf16x8*)&As[row * BK + sl * 8];                \
            }                                                                  \
            for (int j = 0; j < 4; j++) {                                      \
                int row = wn * 64 + j * 16 + lr;                               \
                int sl  = (ks * 4 + qd) ^ (row & 7);                           \
                bfr[j] = *(const bf16x8*)&Bs[row * BK + sl * 8];               \
            }                                                                  \
            for (int i = 0; i < 4; i++)                                        \
                for (int j = 0; j < 4; j++)                                    \
                    acc[i][j] = __builtin_amdgcn_mfma_f32_16x16x32_bf16(       \
                        af[i], bfr[j], acc[i][j], 0, 0, 0);                    \
        }                                                                      \
        __syncthreads();                                                       \
    }

// Fused SwiGLU: Hbuf = silu(Xp@Wg+bg) * (Xp@Wu+bu). BM=128 x BN=64, K=FD=256.
__global__ __launch_bounds__(256, 3) void k_swiglu(
    const bf16* __restrict__ Xp, const bf16* __restrict__ Wgt, const bf16* __restrict__ Wut,
    const float* __restrict__ bg, const float* __restrict__ bu, bf16* __restrict__ Hbuf,
    const int* __restrict__ tileE, const int* __restrict__ tileR,
    const int* __restrict__ off, const int* __restrict__ ntp)
{
    __shared__ bf16 As [BM * BK];        // 16 KB
    __shared__ bf16 Bgs[64 * BK];        // 8 KB
    __shared__ bf16 Bus[64 * BK];        // 8 KB
    DECODE_TILE(16, 64)

    f32x4 accg[4][2] = {};
    f32x4 accu[4][2] = {};
    const bf16* Ab  = Xp  + (size_t)(base + row0) * FD;
    const bf16* Bgb = Wgt + ((size_t)e * HD + n0) * FD;
    const bf16* Bub = Wut + ((size_t)e * HD + n0) * FD;

    for (int k0 = 0; k0 < FD; k0 += BK) {
        for (int s = 0; s < 4; s++) {                  // A: 1024 chunks
            int ci = tid + s * 256;
            int row = ci >> 3;
            int jg  = (ci & 7) ^ (row & 7);
            int mc  = row < valid ? row : valid - 1;
            cp16(Ab + (size_t)mc * FD + k0 + jg * 8, &As[ci * 8]);
        }
        for (int s = 0; s < 2; s++) {                  // Bg,Bu: 512 chunks each
            int ci = tid + s * 256;
            int row = ci >> 3;
            int jg  = (ci & 7) ^ (row & 7);
            cp16(Bgb + (size_t)row * FD + k0 + jg * 8, &Bgs[ci * 8]);
            cp16(Bub + (size_t)row * FD + k0 + jg * 8, &Bus[ci * 8]);
        }
        __syncthreads();
        for (int ks = 0; ks < 2; ks++) {
            bf16x8 af[4], bgf[2], buf[2];
            for (int i = 0; i < 4; i++) {
                int row = wm * 64 + i * 16 + lr;
                int sl  = (ks * 4 + qd) ^ (row & 7);
                af[i] = *(const bf16x8*)&As[row * BK + sl * 8];
            }
            for (int j = 0; j < 2; j++) {
                int row = wn * 32 + j * 16 + lr;
                int sl  = (ks * 4 + qd) ^ (row & 7);
                bgf[j] = *(const bf16x8*)&Bgs[row * BK + sl * 8];
                buf[j] = *(const bf16x8*)&Bus[row * BK + sl * 8];
            }
            for (int i = 0; i < 4; i++)
                for (int j = 0; j < 2; j++) {
                    accg[i][j] = __builtin_amdgcn_mfma_f32_16x16x32_bf16(af[i], bgf[j], accg[i][j], 0, 0, 0);
                    accu[i][j] = __builtin_amdgcn_mfma_f32_16x16x32_bf16(af[i], buf[j], accu[i][j], 0, 0, 0);
                }
        }
        __syncthreads();
    }
    for (int i = 0; i < 4; i++) {
        int rb = wm * 64 + i * 16 + qd * 4;
        for (int r = 0; r < 4; r++) {
            int m = rb + r;
            if (m >= valid) continue;
            size_t orow = (size_t)(base + row0 + m) * HD;
            for (int j = 0; j < 2; j++) {
                int n = n0 + wn * 32 + j * 16 + lr;
                float g = accg[i][j][r] + bg[e * HD + n];
                float u = accu[i][j][r] + bu[e * HD + n];
                float h = g * u / (1.f + __expf(-g));   // silu(g)*u
                Hbuf[orow + n] = (bf16)h;
            }
        }
    }
}

// ================= gemm2: 256x256 8-phase pipeline (asm ds_read) ==========
#define STG_A(buf, h, k0)                                                      \
    { _Pragma("unroll") for (int s = 0; s < 2; s++) {                          \
        int rr = (h) * 128 + s * 64 + rbase;                                   \
        int mr = rr < valid ? rr : valid - 1;                                  \
        cp16(Ab + (size_t)mr * HD + (k0) + jg8,                                \
             &sm[(buf) * 16384 + (h) * 8192 + (s * 512 + tid) * 8]); } }

#define STG_B(buf, h, k0)                                                      \
    { _Pragma("unroll") for (int s = 0; s < 2; s++) {                          \
        int rr = (h) * 128 + s * 64 + rbase;                                   \
        cp16(Bb + (size_t)rr * HD + (k0) + jg8,                                \
             &sm[32768 + (buf) * 16384 + (h) * 8192 + (s * 512 + tid) * 8]); } }

#define PHASE(p, STAGE, DOVW)                                                  \
    {                                                                          \
        bf16x8 af[2][2];                                                       \
        _Pragma("unroll") for (int ii = 0; ii < 2; ii++) {                     \
            uint32_t ro = abase + (2 * (p) + ii) * 2048u;                      \
            af[ii][0] = dsr128(ro + sl0b);                                     \
            af[ii][1] = dsr128(ro + sl1b);                                     \
        }                                                                      \
        STAGE;                                                                 \
        if (DOVW) { asm volatile("s_waitcnt vmcnt(4)" ::: "memory"); }         \
        asm volatile("" ::: "memory");                                         \
        __builtin_amdgcn_s_barrier();                                          \
        asm volatile("s_waitcnt lgkmcnt(0)" ::: "memory");                     \
        __builtin_amdgcn_sched_barrier(0);                                     \
        __builtin_amdgcn_s_setprio(1);                                         \
        _Pragma("unroll") for (int ii = 0; ii < 2; ii++)                       \
        _Pragma("unroll") for (int j = 0; j < 4; j++) {                        \
            acc[2 * (p) + ii][j] = __builtin_amdgcn_mfma_f32_16x16x32_bf16(    \
                af[ii][0], bfr[j][0], acc[2 * (p) + ii][j], 0, 0, 0);          \
            acc[2 * (p) + ii][j] = __builtin_amdgcn_mfma_f32_16x16x32_bf16(    \
                af[ii][1], bfr[j][1], acc[2 * (p) + ii][j], 0, 0, 0);          \
        }                                                                      \
        __builtin_amdgcn_s_setprio(0);                                         \
        asm volatile("" ::: "memory");                                         \
        __builtin_amdgcn_s_barrier();                                          \
        asm volatile("" ::: "memory");                                         \
    }

__global__ __launch_bounds__(512, 1) void k_gemm2_8ph(
    const bf16* __restrict__ Ain, const bf16* __restrict__ Bt,
    const float* __restrict__ bias, bf16* __restrict__ Out,
    const int* __restrict__ tileE2, const int* __restrict__ tileR2,
    const int* __restrict__ off, const int* __restrict__ ntp2)
{
    extern __shared__ bf16 sm[];   // [2][256*64] A, then [2][256*64] B = 128 KiB
    int L = blockIdx.x;
    int xcd = L & 7, tq = L >> 3;
    int ny = tq & 3, Rhi = tq >> 2;
    int R = Rhi * 8 + xcd;
    if (R >= *ntp2) return;
    int e    = tileE2[R];
    int row0 = tileR2[R] * 256;
    int base = off[e];
    int valid = off[e + 1] - base - row0; if (valid > 256) valid = 256;
    int n0 = ny * 256;
    int tid = threadIdx.x;
    int lane = tid & 63, wv = tid >> 6;
    int wm = wv >> 2, wn = wv & 3;          // 2M x 4N waves
    int lr = lane & 15, qd = lane >> 4;
    uint32_t smb = (uint32_t)(uintptr_t)(__attribute__((address_space(3))) bf16*)sm;
    uint32_t sl0b = 16u * (uint32_t)(qd ^ (lr & 7));        // swizzled slot ks=0
    uint32_t sl1b = 16u * (uint32_t)((4 + qd) ^ (lr & 7));  // ks=1
    uint32_t aW = smb + (uint32_t)(wm * 128 + lr) * 128u;          // A wave base
    uint32_t bW = smb + 65536u + (uint32_t)(wn * 64 + lr) * 128u;  // B wave base
    int rbase = tid >> 3;                   // staging dest row base (0..63)
    int jg8 = ((tid & 7) ^ (rbase & 7)) * 8; // pre-swizzled global chunk

    const bf16* Ab = Ain + (size_t)(base + row0) * HD;
    const bf16* Bb = Bt + ((size_t)e * HD + n0) * HD;

    f32x4 acc[8][4] = {};

    // ---- prologue: stage B(0), A(0) -> buf0; B(1) -> buf1 ----
    STG_B(0, 0, 0) STG_B(0, 1, 0)
    STG_A(0, 0, 0) STG_A(0, 1, 0)
    STG_B(1, 0, 64) STG_B(1, 1, 64)
    asm volatile("s_waitcnt vmcnt(4)" ::: "memory");   // B(0),A(0) landed
    asm volatile("" ::: "memory");
    __builtin_amdgcn_s_barrier();
    asm volatile("" ::: "memory");

    for (int t = 0; t < 16; t++) {
        int b = t & 1;
        uint32_t bufo = (uint32_t)b * 32768u;
        uint32_t abase = aW + bufo;
        uint32_t bbase = bW + bufo;
        int kA = (t + 1 < 16) ? (t + 1) * 64 : 0;   // clamped (dead data ok)
        int kB = (t + 2 < 16) ? (t + 2) * 64 : 0;
        bf16x8 bfr[4][2];
        #pragma unroll
        for (int j = 0; j < 4; j++) {               // B-frags register-resident
            bfr[j][0] = dsr128(bbase + (uint32_t)j * 2048u + sl0b);
            bfr[j][1] = dsr128(bbase + (uint32_t)j * 2048u + sl1b);
        }
        PHASE(0, STG_A(b ^ 1, 0, kA), 0)
        PHASE(1, STG_A(b ^ 1, 1, kA), 0)
        PHASE(2, STG_B(b, 0, kB), 0)
        PHASE(3, STG_B(b, 1, kB), 1)
    }
    asm volatile("s_waitcnt vmcnt(0)" ::: "memory"); // drain before LDS release

    // ---- epilogue: bias + ReLU, bf16 store ----
    float bj[4];
    #pragma unroll
    for (int j = 0; j < 4; j++) bj[j] = bias[e * HD + n0 + wn * 64 + j * 16 + lr];
    #pragma unroll
    for (int i = 0; i < 8; i++) {
        int rb = wm * 128 + i * 16 + qd * 4;
        #pragma unroll
        for (int r = 0; r < 4; r++) {
            int m = rb + r;
            if (m >= valid) continue;
            size_t orow = (size_t)(base + row0 + m) * HD;
            #pragma unroll
            for (int j = 0; j < 4; j++) {
                int n = n0 + wn * 64 + j * 16 + lr;
                float v = acc[i][j][r] + bj[j];
                Out[orow + n] = (bf16)(v > 0.f ? v : 0.f);
            }
        }
    }
}

// gemm3: out[perm] = H2@W2 + b2 (fp32 scatter). K=HD, NTY=2.
__global__ __launch_bounds__(256, 3) void k_gemm3(
    const bf16* __restrict__ Ain, const bf16* __restrict__ Bt, const float* __restrict__ bias,
    float* __restrict__ out, const int* __restrict__ perm,
    const int* __restrict__ tileE, const int* __restrict__ tileR,
    const int* __restrict__ off, const int* __restrict__ ntp)
{
    __shared__ bf16 As[BM * BK];
    __shared__ bf16 Bs[BN * BK];
    DECODE_TILE(2, BN)
    f32x4 acc[4][4] = {};
    const bf16* Ab = Ain + (size_t)(base + row0) * HD;
    const bf16* Bb = Bt  + ((size_t)e * OD + n0) * HD;
    GEMM_KLOOP(HD)
    for (int i = 0; i < 4; i++) {
        int rb = wm * 64 + i * 16 + qd * 4;
        for (int r = 0; r < 4; r++) {
            int m = rb + r;
            if (m >= valid) continue;
            int tok = perm[base + row0 + m];
            size_t orow = (size_t)tok * OD;
            for (int j = 0; j < 4; j++) {
                int n = n0 + wn * 64 + j * 16 + lr;
                out[orow + n] = acc[i][j][r] + bias[e * OD + n];
            }
        }
    }
}

// ---------------- launch ----------------
extern "C" void kernel_launch(void* const* d_in, const int* in_sizes, int n_in,
                              void* d_out, int out_size, void* d_ws, size_t ws_size,
                              hipStream_t stream) {
    const float* x   = (const float*)d_in[0];
    const int*   sel = (const int*)d_in[1];
    const float* Wg  = (const float*)d_in[2];
    const float* bg  = (const float*)d_in[3];
    const float* Wu  = (const float*)d_in[4];
    const float* bu  = (const float*)d_in[5];
    const float* W1  = (const float*)d_in[6];
    const float* b1  = (const float*)d_in[7];
    const float* W2  = (const float*)d_in[8];
    const float* b2  = (const float*)d_in[9];
    float* out = (float*)d_out;

    char* ws = (char*)d_ws;
    int* cnt    = (int*)(ws + O_CNT);
    int* cur    = (int*)(ws + O_CUR);
    int* off    = (int*)(ws + O_OFF);
    int* nt     = (int*)(ws + O_NT);
    int* nt2    = (int*)(ws + O_NT2);
    int* tileE  = (int*)(ws + O_TE);
    int* tileE2 = (int*)(ws + O_TE2);
    int* tileR  = (int*)(ws + O_TR);
    int* tileR2 = (int*)(ws + O_TR2);
    int* perm   = (int*)(ws + O_PERM);
    bf16* Xp    = (bf16*)(ws + O_XP);
    bf16* Wgt   = (bf16*)(ws + O_WG);
    bf16* Wut   = (bf16*)(ws + O_WU);
    bf16* W1t   = (bf16*)(ws + O_W1);
    bf16* W2t   = (bf16*)(ws + O_W2);
    bf16* Hbuf  = (bf16*)(ws + O_H);
    bf16* H2    = (bf16*)(ws + O_H2);

    static bool s_attr = false;
    if (!s_attr) {
        hipFuncSetAttribute((const void*)k_gemm2_8ph,
                            hipFuncAttributeMaxDynamicSharedMemorySize, 131072);
        s_attr = true;
    }

    hipMemsetAsync(ws, 0, 256, stream);

    k_hist   <<<NTOK / 256, 256, 0, stream>>>(sel, cnt);
    k_plan   <<<1, 64, 0, stream>>>(cnt, off, tileE, tileR, nt, tileE2, tileR2, nt2);
    k_scatter<<<NTOK / 256, 256, 0, stream>>>(sel, off, cur, perm);
    k_gather <<<NTOK * 64 / 256, 256, 0, stream>>>(x, perm, Xp);

    k_transpose_all<<<NEXP * TPE, 256, 0, stream>>>(Wg, Wgt, Wu, Wut, W1, W1t, W2, W2t);

    k_swiglu<<<RT8 * 16 * 8, 256, 0, stream>>>(Xp, Wgt, Wut, bg, bu, Hbuf,
                                               tileE, tileR, off, nt);
    k_gemm2_8ph<<<RT2_8 * 4 * 8, 512, 131072, stream>>>(Hbuf, W1t, b1, H2,
                                                        tileE2, tileR2, off, nt2);
    k_gemm3 <<<RT8 * 2 * 8, 256, 0, stream>>>(H2, W2t, b2, out, perm,
                                              tileE, tileR, off, nt);
}

// Round 4
// 345.848 us; speedup vs baseline: 1.0671x; 1.0671x over previous
//
#include <hip/hip_runtime.h>
#include <hip/hip_bf16.h>
#include <cstdint>
#include <cstddef>

// Problem constants
#define NTOK 32768   // P*N*K token-copies
#define FD   256     // input feature dim
#define HD   1024    // hidden dim
#define OD   256     // output dim
#define NEXP 8

// GEMM tiling
#define BM 128
#define BN 128
#define BK 64
#define RT8 34       // ceil(max 128-row tiles / 8)

typedef __bf16 bf16;
typedef __bf16 bf16x8 __attribute__((ext_vector_type(8)));
typedef __bf16 bf16x4 __attribute__((ext_vector_type(4)));
typedef float  f32x4  __attribute__((ext_vector_type(4)));

// async global->LDS, 16 B per lane. LDS dst MUST be wave-uniform base + lane*16.
__device__ __forceinline__ void cp16(const void* g, void* l) {
    __builtin_amdgcn_global_load_lds(
        (const __attribute__((address_space(1))) void*)g,
        (__attribute__((address_space(3))) void*)l, 16, 0, 0);
}

// ---- workspace layout (bytes) ----
static const size_t O_CNT  = 0;          // int[8]
static const size_t O_CUR  = 64;         // int[8]
static const size_t O_OFF  = 128;        // int[9]
static const size_t O_NT   = 192;        // int[1]
static const size_t O_NT2  = 196;        // int[1]  (256-row tile count, unused)
static const size_t O_TE   = 1024;       // int[<=264 used]
static const size_t O_TE2  = 2112;       // int[<=136]
static const size_t O_TR   = 3072;       // int[<=264 used]
static const size_t O_TR2  = 4160;       // int[<=136]
static const size_t O_PERM = 5120;       // int[NTOK]
static const size_t O_XP   = 136192;     // bf16 [NTOK][FD]    (16 MB)
static const size_t O_WG   = 16913408;   // bf16 [E][HD][FD]   (4 MB)
static const size_t O_WU   = 21107712;   // bf16 [E][HD][FD]   (4 MB)
static const size_t O_W1   = 25302016;   // bf16 [E][HD][HD]   (16 MB)
static const size_t O_W2   = 42079232;   // bf16 [E][OD][HD]   (4 MB)
static const size_t O_H    = 46273536;   // bf16 [NTOK][HD]    (64 MB) Hbuf
static const size_t O_H2   = 113382400;  // bf16 [NTOK][HD]    (64 MB) H2

// ---------------- routing ----------------
__global__ void k_hist(const int* __restrict__ sel, int* __restrict__ cnt) {
    __shared__ int lcnt[NEXP];
    if (threadIdx.x < NEXP) lcnt[threadIdx.x] = 0;
    __syncthreads();
    int t = blockIdx.x * 256 + threadIdx.x;   // NTOK % 256 == 0
    atomicAdd(&lcnt[sel[t]], 1);
    __syncthreads();
    if (threadIdx.x < NEXP) atomicAdd(&cnt[threadIdx.x], lcnt[threadIdx.x]);
}

__global__ void k_plan(const int* __restrict__ cnt, int* __restrict__ off,
                       int* __restrict__ tileE, int* __restrict__ tileR,
                       int* __restrict__ nt,
                       int* __restrict__ tileE2, int* __restrict__ tileR2,
                       int* __restrict__ nt2) {
    if (threadIdx.x == 0 && blockIdx.x == 0) {
        int o = 0;
        for (int e = 0; e < NEXP; e++) { off[e] = o; o += cnt[e]; }
        off[NEXP] = o;
        int n = 0;
        for (int e = 0; e < NEXP; e++) {
            int c = cnt[e];
            int nte = (c + BM - 1) / BM;
            for (int r = 0; r < nte; r++) { tileE[n] = e; tileR[n] = r; n++; }
        }
        *nt = n;
        int n2 = 0;
        for (int e = 0; e < NEXP; e++) {
            int c = cnt[e];
            int nte = (c + 255) / 256;
            for (int r = 0; r < nte; r++) { tileE2[n2] = e; tileR2[n2] = r; n2++; }
        }
        *nt2 = n2;
    }
}

__global__ void k_scatter(const int* __restrict__ sel, const int* __restrict__ off,
                          int* __restrict__ cur, int* __restrict__ perm) {
    __shared__ int lcnt[NEXP];
    __shared__ int lbase[NEXP];
    if (threadIdx.x < NEXP) lcnt[threadIdx.x] = 0;
    __syncthreads();
    int t = blockIdx.x * 256 + threadIdx.x;
    int e = sel[t];
    int rank = atomicAdd(&lcnt[e], 1);
    __syncthreads();
    if (threadIdx.x < NEXP)
        lbase[threadIdx.x] = atomicAdd(&cur[threadIdx.x], lcnt[threadIdx.x]);
    __syncthreads();
    perm[off[e] + lbase[e] + rank] = t;
}

__global__ void k_gather(const float* __restrict__ x, const int* __restrict__ perm,
                         bf16* __restrict__ Xp) {
    int gid = blockIdx.x * 256 + threadIdx.x;
    int pos = gid >> 6;
    int c   = gid & 63;
    int tok = perm[pos];
    float4 v = ((const float4*)x)[(size_t)tok * 64 + c];
    bf16x4 o;
    o.x = (bf16)v.x; o.y = (bf16)v.y; o.z = (bf16)v.z; o.w = (bf16)v.w;
    *(bf16x4*)&Xp[(size_t)pos * FD + c * 4] = o;
}

// All 4 weight transposes in ONE launch. W [E][K][N] fp32 -> Wt [E][N][K] bf16.
#define TPE 448
__global__ void k_transpose_all(const float* __restrict__ Wg, bf16* __restrict__ Wgt,
                                const float* __restrict__ Wu, bf16* __restrict__ Wut,
                                const float* __restrict__ W1, bf16* __restrict__ W1t,
                                const float* __restrict__ W2, bf16* __restrict__ W2t) {
    __shared__ float tile[64][65];
    int b  = blockIdx.x;
    int e  = b / TPE;
    int tt = b % TPE;
    const float* Ws; bf16* Wd; int K, N;
    if (tt < 64)       { Ws = Wg; Wd = Wgt; K = FD; N = HD; }
    else if (tt < 128) { Ws = Wu; Wd = Wut; K = FD; N = HD; tt -= 64; }
    else if (tt < 384) { Ws = W1; Wd = W1t; K = HD; N = HD; tt -= 128; }
    else               { Ws = W2; Wd = W2t; K = HD; N = OD; tt -= 384; }
    int nk = K / 64;
    int k0 = (tt % nk) * 64, n0 = (tt / nk) * 64;
    Ws += (size_t)e * K * N;
    Wd += (size_t)e * K * N;
    int t = threadIdx.x;
    for (int q = 0; q < 4; q++) {
        int lin = t + q * 256;
        int r = lin >> 4, c4 = (lin & 15) * 4;
        float4 v = *(const float4*)&Ws[(size_t)(k0 + r) * N + n0 + c4];
        tile[r][c4] = v.x; tile[r][c4+1] = v.y; tile[r][c4+2] = v.z; tile[r][c4+3] = v.w;
    }
    __syncthreads();
    for (int q = 0; q < 2; q++) {   // 64 n * 8 chunks = 512 items
        int lin = t + q * 256;
        int n = lin >> 3, k8 = (lin & 7) * 8;
        bf16x8 o;
        for (int i = 0; i < 8; i++) o[i] = (bf16)tile[k8 + i][n];
        *(bf16x8*)&Wd[(size_t)(n0 + n) * K + k0 + k8] = o;
    }
}

// ---------------- GEMM kernels ----------------
// MFMA 16x16x32 bf16 (HW-verified layouts). BK=64: 2 k-steps per barrier.
// LDS: unpadded [rows][64], XOR chunk swizzle over 8 chunks/row:
//   slot s holds global chunk s ^ (row&7); read slot (ks*4+qd)^(row&7).
// XCD swizzle: 1D grid, xcd=L&7 -> all n-tiles of a row-tile on one XCD.

#define DECODE_TILE(NTY, BNE)                                                  \
    int L = blockIdx.x;                                                        \
    int xcd = L & 7; int tq = L >> 3;                                          \
    int ny  = tq % (NTY); int Rhi = tq / (NTY);                                \
    int R   = Rhi * 8 + xcd;                                                   \
    if (R >= *ntp) return;                                                     \
    int e    = tileE[R];                                                       \
    int row0 = tileR[R] * BM;                                                  \
    int base = off[e];                                                         \
    int valid = off[e + 1] - base - row0; if (valid > BM) valid = BM;          \
    int n0 = ny * (BNE);                                                       \
    int tid = threadIdx.x;                                                     \
    int lane = tid & 63, wv = tid >> 6;                                        \
    int wm = wv & 1, wn = wv >> 1;                                             \
    int lr = lane & 15, qd = lane >> 4;

#define GEMM_KLOOP(KDIM)                                                       \
    for (int k0 = 0; k0 < (KDIM); k0 += BK) {                                  \
        for (int s = 0; s < 4; s++) {                                          \
            int ci = tid + s * 256;                                            \
            int row = ci >> 3;                                                 \
            int jg  = (ci & 7) ^ (row & 7);                                    \
            int mc  = row < valid ? row : valid - 1;                           \
            cp16(Ab + (size_t)mc  * (KDIM) + k0 + jg * 8, &As[ci * 8]);        \
            cp16(Bb + (size_t)row * (KDIM) + k0 + jg * 8, &Bs[ci * 8]);        \
        }                                                                      \
        __syncthreads();                                                       \
        for (int ks = 0; ks < 2; ks++) {                                       \
            bf16x8 af[4], bfr[4];                                              \
            for (int i = 0; i < 4; i++) {                                      \
                int row = wm * 64 + i * 16 + lr;                               \
                int sl  = (ks * 4 + qd) ^ (row & 7);                           \
                af[i] = *(const bf16x8*)&As[row * BK + sl * 8];                \
            }                                                                  \
            for (int j = 0; j < 4; j++) {                                      \
                int row = wn * 64 + j * 16 + lr;                               \
                int sl  = (ks * 4 + qd) ^ (row & 7);                           \
                bfr[j] = *(const bf16x8*)&Bs[row * BK + sl * 8];               \
            }                                                                  \
            for (int i = 0; i < 4; i++)                                        \
                for (int j = 0; j < 4; j++)                                    \
                    acc[i][j] = __builtin_amdgcn_mfma_f32_16x16x32_bf16(       \
                        af[i], bfr[j], acc[i][j], 0, 0, 0);                    \
        }                                                                      \
        __syncthreads();                                                       \
    }

// Fused SwiGLU: Hbuf = silu(Xp@Wg+bg) * (Xp@Wu+bu).
// BM=128 x BN=128 (was BN=64): 64 MFMA per 48 KB staged (+33% compute
// density vs 32 MFMA / 32 KB). Same f32 accumulate + silu numerics.
// acc 2x[4][4] = 128 AGPR -> ~2 blocks/CU; LDS 48 KB.
__global__ __launch_bounds__(256, 2) void k_swiglu(
    const bf16* __restrict__ Xp, const bf16* __restrict__ Wgt, const bf16* __restrict__ Wut,
    const float* __restrict__ bg, const float* __restrict__ bu, bf16* __restrict__ Hbuf,
    const int* __restrict__ tileE, const int* __restrict__ tileR,
    const int* __restrict__ off, const int* __restrict__ ntp)
{
    __shared__ bf16 As [BM * BK];        // 16 KB
    __shared__ bf16 Bgs[BN * BK];        // 16 KB
    __shared__ bf16 Bus[BN * BK];        // 16 KB
    DECODE_TILE(8, 128)

    f32x4 accg[4][4] = {};
    f32x4 accu[4][4] = {};
    const bf16* Ab  = Xp  + (size_t)(base + row0) * FD;
    const bf16* Bgb = Wgt + ((size_t)e * HD + n0) * FD;
    const bf16* Bub = Wut + ((size_t)e * HD + n0) * FD;

    for (int k0 = 0; k0 < FD; k0 += BK) {
        for (int s = 0; s < 4; s++) {                  // A,Bg,Bu: 1024 chunks each
            int ci = tid + s * 256;
            int row = ci >> 3;
            int jg  = (ci & 7) ^ (row & 7);
            int mc  = row < valid ? row : valid - 1;
            cp16(Ab  + (size_t)mc  * FD + k0 + jg * 8, &As [ci * 8]);
            cp16(Bgb + (size_t)row * FD + k0 + jg * 8, &Bgs[ci * 8]);
            cp16(Bub + (size_t)row * FD + k0 + jg * 8, &Bus[ci * 8]);
        }
        __syncthreads();
        for (int ks = 0; ks < 2; ks++) {
            bf16x8 af[4], bgf[4], buf[4];
            for (int i = 0; i < 4; i++) {
                int row = wm * 64 + i * 16 + lr;
                int sl  = (ks * 4 + qd) ^ (row & 7);
                af[i] = *(const bf16x8*)&As[row * BK + sl * 8];
            }
            for (int j = 0; j < 4; j++) {
                int row = wn * 64 + j * 16 + lr;
                int sl  = (ks * 4 + qd) ^ (row & 7);
                bgf[j] = *(const bf16x8*)&Bgs[row * BK + sl * 8];
                buf[j] = *(const bf16x8*)&Bus[row * BK + sl * 8];
            }
            for (int i = 0; i < 4; i++)
                for (int j = 0; j < 4; j++) {
                    accg[i][j] = __builtin_amdgcn_mfma_f32_16x16x32_bf16(af[i], bgf[j], accg[i][j], 0, 0, 0);
                    accu[i][j] = __builtin_amdgcn_mfma_f32_16x16x32_bf16(af[i], buf[j], accu[i][j], 0, 0, 0);
                }
        }
        __syncthreads();
    }
    for (int i = 0; i < 4; i++) {
        int rb = wm * 64 + i * 16 + qd * 4;
        for (int r = 0; r < 4; r++) {
            int m = rb + r;
            if (m >= valid) continue;
            size_t orow = (size_t)(base + row0 + m) * HD;
            for (int j = 0; j < 4; j++) {
                int n = n0 + wn * 64 + j * 16 + lr;
                float g = accg[i][j][r] + bg[e * HD + n];
                float u = accu[i][j][r] + bu[e * HD + n];
                float h = g * u / (1.f + __expf(-g));   // silu(g)*u
                Hbuf[orow + n] = (bf16)h;
            }
        }
    }
}

// gemm2: H2 = relu(Hbuf@W1 + b1). K=HD, NTY=8.  (proven 128^2 structure)
__global__ __launch_bounds__(256, 3) void k_gemm2(
    const bf16* __restrict__ Ain, const bf16* __restrict__ Bt, const float* __restrict__ bias,
    bf16* __restrict__ Out,
    const int* __restrict__ tileE, const int* __restrict__ tileR,
    const int* __restrict__ off, const int* __restrict__ ntp)
{
    __shared__ bf16 As[BM * BK];   // 16 KB
    __shared__ bf16 Bs[BN * BK];   // 16 KB
    DECODE_TILE(8, BN)
    f32x4 acc[4][4] = {};
    const bf16* Ab = Ain + (size_t)(base + row0) * HD;
    const bf16* Bb = Bt  + ((size_t)e * HD + n0) * HD;
    GEMM_KLOOP(HD)
    for (int i = 0; i < 4; i++) {
        int rb = wm * 64 + i * 16 + qd * 4;
        for (int r = 0; r < 4; r++) {
            int m = rb + r;
            if (m >= valid) continue;
            size_t orow = (size_t)(base + row0 + m) * HD;
            for (int j = 0; j < 4; j++) {
                int n = n0 + wn * 64 + j * 16 + lr;
                float v = acc[i][j][r] + bias[e * HD + n];
                Out[orow + n] = (bf16)(v > 0.f ? v : 0.f);
            }
        }
    }
}

// gemm3: out[perm] = H2@W2 + b2 (fp32 scatter). K=HD, NTY=2.
__global__ __launch_bounds__(256, 3) void k_gemm3(
    const bf16* __restrict__ Ain, const bf16* __restrict__ Bt, const float* __restrict__ bias,
    float* __restrict__ out, const int* __restrict__ perm,
    const int* __restrict__ tileE, const int* __restrict__ tileR,
    const int* __restrict__ off, const int* __restrict__ ntp)
{
    __shared__ bf16 As[BM * BK];
    __shared__ bf16 Bs[BN * BK];
    DECODE_TILE(2, BN)
    f32x4 acc[4][4] = {};
    const bf16* Ab = Ain + (size_t)(base + row0) * HD;
    const bf16* Bb = Bt  + ((size_t)e * OD + n0) * HD;
    GEMM_KLOOP(HD)
    for (int i = 0; i < 4; i++) {
        int rb = wm * 64 + i * 16 + qd * 4;
        for (int r = 0; r < 4; r++) {
            int m = rb + r;
            if (m >= valid) continue;
            int tok = perm[base + row0 + m];
            size_t orow = (size_t)tok * OD;
            for (int j = 0; j < 4; j++) {
                int n = n0 + wn * 64 + j * 16 + lr;
                out[orow + n] = acc[i][j][r] + bias[e * OD + n];
            }
        }
    }
}

// ---------------- launch ----------------
extern "C" void kernel_launch(void* const* d_in, const int* in_sizes, int n_in,
                              void* d_out, int out_size, void* d_ws, size_t ws_size,
                              hipStream_t stream) {
    const float* x   = (const float*)d_in[0];
    const int*   sel = (const int*)d_in[1];
    const float* Wg  = (const float*)d_in[2];
    const float* bg  = (const float*)d_in[3];
    const float* Wu  = (const float*)d_in[4];
    const float* bu  = (const float*)d_in[5];
    const float* W1  = (const float*)d_in[6];
    const float* b1  = (const float*)d_in[7];
    const float* W2  = (const float*)d_in[8];
    const float* b2  = (const float*)d_in[9];
    float* out = (float*)d_out;

    char* ws = (char*)d_ws;
    int* cnt    = (int*)(ws + O_CNT);
    int* cur    = (int*)(ws + O_CUR);
    int* off    = (int*)(ws + O_OFF);
    int* nt     = (int*)(ws + O_NT);
    int* nt2    = (int*)(ws + O_NT2);
    int* tileE  = (int*)(ws + O_TE);
    int* tileE2 = (int*)(ws + O_TE2);
    int* tileR  = (int*)(ws + O_TR);
    int* tileR2 = (int*)(ws + O_TR2);
    int* perm   = (int*)(ws + O_PERM);
    bf16* Xp    = (bf16*)(ws + O_XP);
    bf16* Wgt   = (bf16*)(ws + O_WG);
    bf16* Wut   = (bf16*)(ws + O_WU);
    bf16* W1t   = (bf16*)(ws + O_W1);
    bf16* W2t   = (bf16*)(ws + O_W2);
    bf16* Hbuf  = (bf16*)(ws + O_H);
    bf16* H2    = (bf16*)(ws + O_H2);

    hipMemsetAsync(ws, 0, 256, stream);

    k_hist   <<<NTOK / 256, 256, 0, stream>>>(sel, cnt);
    k_plan   <<<1, 64, 0, stream>>>(cnt, off, tileE, tileR, nt, tileE2, tileR2, nt2);
    k_scatter<<<NTOK / 256, 256, 0, stream>>>(sel, off, cur, perm);
    k_gather <<<NTOK * 64 / 256, 256, 0, stream>>>(x, perm, Xp);

    k_transpose_all<<<NEXP * TPE, 256, 0, stream>>>(Wg, Wgt, Wu, Wut, W1, W1t, W2, W2t);

    // swiglu now BN=128 -> NTY = HD/128 = 8
    k_swiglu<<<RT8 * 8 * 8, 256, 0, stream>>>(Xp, Wgt, Wut, bg, bu, Hbuf,
                                              tileE, tileR, off, nt);
    k_gemm2 <<<RT8 * 8 * 8, 256, 0, stream>>>(Hbuf, W1t, b1, H2,
                                              tileE, tileR, off, nt);
    k_gemm3 <<<RT8 * 2 * 8, 256, 0, stream>>>(H2, W2t, b2, out, perm,
                                              tileE, tileR, off, nt);
}

// Round 5
// 336.684 us; speedup vs baseline: 1.0962x; 1.0272x over previous
//
#include <hip/hip_runtime.h>
#include <hip/hip_bf16.h>
#include <cstdint>
#include <cstddef>

// Problem constants
#define NTOK 32768   // P*N*K token-copies
#define FD   256     // input feature dim
#define HD   1024    // hidden dim
#define OD   256     // output dim
#define NEXP 8

// GEMM tiling
#define BM 128
#define BN 128
#define BK 64
#define RT8 34       // ceil(max 128-row tiles / 8)

typedef __bf16 bf16;
typedef __bf16 bf16x8 __attribute__((ext_vector_type(8)));
typedef __bf16 bf16x4 __attribute__((ext_vector_type(4)));
typedef float  f32x4  __attribute__((ext_vector_type(4)));

// async global->LDS, 16 B per lane. LDS dst MUST be wave-uniform base + lane*16.
__device__ __forceinline__ void cp16(const void* g, void* l) {
    __builtin_amdgcn_global_load_lds(
        (const __attribute__((address_space(1))) void*)g,
        (__attribute__((address_space(3))) void*)l, 16, 0, 0);
}

// ---- workspace layout (bytes) ----
static const size_t O_CNT  = 0;          // int[8]
static const size_t O_CUR  = 64;         // int[8]
static const size_t O_OFF  = 128;        // int[9]
static const size_t O_NT   = 192;        // int[1]
static const size_t O_NT2  = 196;        // int[1]  (256-row tile count, unused)
static const size_t O_TE   = 1024;       // int[<=264 used]
static const size_t O_TE2  = 2112;       // int[<=136]
static const size_t O_TR   = 3072;       // int[<=264 used]
static const size_t O_TR2  = 4160;       // int[<=136]
static const size_t O_PERM = 5120;       // int[NTOK]
static const size_t O_XP   = 136192;     // bf16 [NTOK][FD]    (16 MB)
static const size_t O_WG   = 16913408;   // bf16 [E][HD][FD]   (4 MB)
static const size_t O_WU   = 21107712;   // bf16 [E][HD][FD]   (4 MB)
static const size_t O_W1   = 25302016;   // bf16 [E][HD][HD]   (16 MB)
static const size_t O_W2   = 42079232;   // bf16 [E][OD][HD]   (4 MB)
static const size_t O_H    = 46273536;   // bf16 [NTOK][HD]    (64 MB) Hbuf
static const size_t O_H2   = 113382400;  // bf16 [NTOK][HD]    (64 MB) H2

// ---------------- routing ----------------
__global__ void k_hist(const int* __restrict__ sel, int* __restrict__ cnt) {
    __shared__ int lcnt[NEXP];
    if (threadIdx.x < NEXP) lcnt[threadIdx.x] = 0;
    __syncthreads();
    int t = blockIdx.x * 256 + threadIdx.x;   // NTOK % 256 == 0
    atomicAdd(&lcnt[sel[t]], 1);
    __syncthreads();
    if (threadIdx.x < NEXP) atomicAdd(&cnt[threadIdx.x], lcnt[threadIdx.x]);
}

__global__ void k_plan(const int* __restrict__ cnt, int* __restrict__ off,
                       int* __restrict__ tileE, int* __restrict__ tileR,
                       int* __restrict__ nt,
                       int* __restrict__ tileE2, int* __restrict__ tileR2,
                       int* __restrict__ nt2) {
    if (threadIdx.x == 0 && blockIdx.x == 0) {
        int o = 0;
        for (int e = 0; e < NEXP; e++) { off[e] = o; o += cnt[e]; }
        off[NEXP] = o;
        int n = 0;
        for (int e = 0; e < NEXP; e++) {
            int c = cnt[e];
            int nte = (c + BM - 1) / BM;
            for (int r = 0; r < nte; r++) { tileE[n] = e; tileR[n] = r; n++; }
        }
        *nt = n;
        int n2 = 0;
        for (int e = 0; e < NEXP; e++) {
            int c = cnt[e];
            int nte = (c + 255) / 256;
            for (int r = 0; r < nte; r++) { tileE2[n2] = e; tileR2[n2] = r; n2++; }
        }
        *nt2 = n2;
    }
}

__global__ void k_scatter(const int* __restrict__ sel, const int* __restrict__ off,
                          int* __restrict__ cur, int* __restrict__ perm) {
    __shared__ int lcnt[NEXP];
    __shared__ int lbase[NEXP];
    if (threadIdx.x < NEXP) lcnt[threadIdx.x] = 0;
    __syncthreads();
    int t = blockIdx.x * 256 + threadIdx.x;
    int e = sel[t];
    int rank = atomicAdd(&lcnt[e], 1);
    __syncthreads();
    if (threadIdx.x < NEXP)
        lbase[threadIdx.x] = atomicAdd(&cur[threadIdx.x], lcnt[threadIdx.x]);
    __syncthreads();
    perm[off[e] + lbase[e] + rank] = t;
}

__global__ void k_gather(const float* __restrict__ x, const int* __restrict__ perm,
                         bf16* __restrict__ Xp) {
    int gid = blockIdx.x * 256 + threadIdx.x;
    int pos = gid >> 6;
    int c   = gid & 63;
    int tok = perm[pos];
    float4 v = ((const float4*)x)[(size_t)tok * 64 + c];
    bf16x4 o;
    o.x = (bf16)v.x; o.y = (bf16)v.y; o.z = (bf16)v.z; o.w = (bf16)v.w;
    *(bf16x4*)&Xp[(size_t)pos * FD + c * 4] = o;
}

// All 4 weight transposes in ONE launch. W [E][K][N] fp32 -> Wt [E][N][K] bf16.
#define TPE 448
__global__ void k_transpose_all(const float* __restrict__ Wg, bf16* __restrict__ Wgt,
                                const float* __restrict__ Wu, bf16* __restrict__ Wut,
                                const float* __restrict__ W1, bf16* __restrict__ W1t,
                                const float* __restrict__ W2, bf16* __restrict__ W2t) {
    __shared__ float tile[64][65];
    int b  = blockIdx.x;
    int e  = b / TPE;
    int tt = b % TPE;
    const float* Ws; bf16* Wd; int K, N;
    if (tt < 64)       { Ws = Wg; Wd = Wgt; K = FD; N = HD; }
    else if (tt < 128) { Ws = Wu; Wd = Wut; K = FD; N = HD; tt -= 64; }
    else if (tt < 384) { Ws = W1; Wd = W1t; K = HD; N = HD; tt -= 128; }
    else               { Ws = W2; Wd = W2t; K = HD; N = OD; tt -= 384; }
    int nk = K / 64;
    int k0 = (tt % nk) * 64, n0 = (tt / nk) * 64;
    Ws += (size_t)e * K * N;
    Wd += (size_t)e * K * N;
    int t = threadIdx.x;
    for (int q = 0; q < 4; q++) {
        int lin = t + q * 256;
        int r = lin >> 4, c4 = (lin & 15) * 4;
        float4 v = *(const float4*)&Ws[(size_t)(k0 + r) * N + n0 + c4];
        tile[r][c4] = v.x; tile[r][c4+1] = v.y; tile[r][c4+2] = v.z; tile[r][c4+3] = v.w;
    }
    __syncthreads();
    for (int q = 0; q < 2; q++) {   // 64 n * 8 chunks = 512 items
        int lin = t + q * 256;
        int n = lin >> 3, k8 = (lin & 7) * 8;
        bf16x8 o;
        for (int i = 0; i < 8; i++) o[i] = (bf16)tile[k8 + i][n];
        *(bf16x8*)&Wd[(size_t)(n0 + n) * K + k0 + k8] = o;
    }
}

// ---------------- GEMM kernels ----------------
// MFMA 16x16x32 bf16 (HW-verified layouts). BK=64: 2 k-steps per barrier.
// LDS: unpadded [rows][64], XOR chunk swizzle over 8 chunks/row:
//   slot s holds global chunk s ^ (row&7); read slot (ks*4+qd)^(row&7).
// XCD swizzle: 1D grid, xcd=L&7 -> all n-tiles of a row-tile on one XCD.
// Occupancy: VGPR 60 + AGPR 64 = 124 regs, 32 KB LDS -> 4 blocks/CU fits
// (regs 124*4 waves = 496 <= 512/SIMD; LDS 4*32 = 128 <= 160 KB).

#define DECODE_TILE(NTY, BNE)                                                  \
    int L = blockIdx.x;                                                        \
    int xcd = L & 7; int tq = L >> 3;                                          \
    int ny  = tq % (NTY); int Rhi = tq / (NTY);                                \
    int R   = Rhi * 8 + xcd;                                                   \
    if (R >= *ntp) return;                                                     \
    int e    = tileE[R];                                                       \
    int row0 = tileR[R] * BM;                                                  \
    int base = off[e];                                                         \
    int valid = off[e + 1] - base - row0; if (valid > BM) valid = BM;          \
    int n0 = ny * (BNE);                                                       \
    int tid = threadIdx.x;                                                     \
    int lane = tid & 63, wv = tid >> 6;                                        \
    int wm = wv & 1, wn = wv >> 1;                                             \
    int lr = lane & 15, qd = lane >> 4;

#define GEMM_KLOOP(KDIM)                                                       \
    for (int k0 = 0; k0 < (KDIM); k0 += BK) {                                  \
        for (int s = 0; s < 4; s++) {                                          \
            int ci = tid + s * 256;                                            \
            int row = ci >> 3;                                                 \
            int jg  = (ci & 7) ^ (row & 7);                                    \
            int mc  = row < valid ? row : valid - 1;                           \
            cp16(Ab + (size_t)mc  * (KDIM) + k0 + jg * 8, &As[ci * 8]);        \
            cp16(Bb + (size_t)row * (KDIM) + k0 + jg * 8, &Bs[ci * 8]);        \
        }                                                                      \
        __syncthreads();                                                       \
        for (int ks = 0; ks < 2; ks++) {                                       \
            bf16x8 af[4], bfr[4];                                              \
            for (int i = 0; i < 4; i++) {                                      \
                int row = wm * 64 + i * 16 + lr;                               \
                int sl  = (ks * 4 + qd) ^ (row & 7);                           \
                af[i] = *(const bf16x8*)&As[row * BK + sl * 8];                \
            }                                                                  \
            for (int j = 0; j < 4; j++) {                                      \
                int row = wn * 64 + j * 16 + lr;                               \
                int sl  = (ks * 4 + qd) ^ (row & 7);                           \
                bfr[j] = *(const bf16x8*)&Bs[row * BK + sl * 8];               \
            }                                                                  \
            for (int i = 0; i < 4; i++)                                        \
                for (int j = 0; j < 4; j++)                                    \
                    acc[i][j] = __builtin_amdgcn_mfma_f32_16x16x32_bf16(       \
                        af[i], bfr[j], acc[i][j], 0, 0, 0);                    \
        }                                                                      \
        __syncthreads();                                                       \
    }

// Fused SwiGLU: Hbuf = silu(Xp@Wg+bg) * (Xp@Wu+bu). BM=128 x BN=64, K=FD=256.
// (R0-proven form; BN=128 variant regressed ~15us via occupancy 3->2.)
// acc 64 AGPR + ~60 VGPR, 32 KB LDS -> 4 blocks/CU.
__global__ __launch_bounds__(256, 4) void k_swiglu(
    const bf16* __restrict__ Xp, const bf16* __restrict__ Wgt, const bf16* __restrict__ Wut,
    const float* __restrict__ bg, const float* __restrict__ bu, bf16* __restrict__ Hbuf,
    const int* __restrict__ tileE, const int* __restrict__ tileR,
    const int* __restrict__ off, const int* __restrict__ ntp)
{
    __shared__ bf16 As [BM * BK];        // 16 KB
    __shared__ bf16 Bgs[64 * BK];        // 8 KB
    __shared__ bf16 Bus[64 * BK];        // 8 KB
    DECODE_TILE(16, 64)

    f32x4 accg[4][2] = {};
    f32x4 accu[4][2] = {};
    const bf16* Ab  = Xp  + (size_t)(base + row0) * FD;
    const bf16* Bgb = Wgt + ((size_t)e * HD + n0) * FD;
    const bf16* Bub = Wut + ((size_t)e * HD + n0) * FD;

    for (int k0 = 0; k0 < FD; k0 += BK) {
        for (int s = 0; s < 4; s++) {                  // A: 1024 chunks
            int ci = tid + s * 256;
            int row = ci >> 3;
            int jg  = (ci & 7) ^ (row & 7);
            int mc  = row < valid ? row : valid - 1;
            cp16(Ab + (size_t)mc * FD + k0 + jg * 8, &As[ci * 8]);
        }
        for (int s = 0; s < 2; s++) {                  // Bg,Bu: 512 chunks each
            int ci = tid + s * 256;
            int row = ci >> 3;
            int jg  = (ci & 7) ^ (row & 7);
            cp16(Bgb + (size_t)row * FD + k0 + jg * 8, &Bgs[ci * 8]);
            cp16(Bub + (size_t)row * FD + k0 + jg * 8, &Bus[ci * 8]);
        }
        __syncthreads();
        for (int ks = 0; ks < 2; ks++) {
            bf16x8 af[4], bgf[2], buf[2];
            for (int i = 0; i < 4; i++) {
                int row = wm * 64 + i * 16 + lr;
                int sl  = (ks * 4 + qd) ^ (row & 7);
                af[i] = *(const bf16x8*)&As[row * BK + sl * 8];
            }
            for (int j = 0; j < 2; j++) {
                int row = wn * 32 + j * 16 + lr;
                int sl  = (ks * 4 + qd) ^ (row & 7);
                bgf[j] = *(const bf16x8*)&Bgs[row * BK + sl * 8];
                buf[j] = *(const bf16x8*)&Bus[row * BK + sl * 8];
            }
            for (int i = 0; i < 4; i++)
                for (int j = 0; j < 2; j++) {
                    accg[i][j] = __builtin_amdgcn_mfma_f32_16x16x32_bf16(af[i], bgf[j], accg[i][j], 0, 0, 0);
                    accu[i][j] = __builtin_amdgcn_mfma_f32_16x16x32_bf16(af[i], buf[j], accu[i][j], 0, 0, 0);
                }
        }
        __syncthreads();
    }
    for (int i = 0; i < 4; i++) {
        int rb = wm * 64 + i * 16 + qd * 4;
        for (int r = 0; r < 4; r++) {
            int m = rb + r;
            if (m >= valid) continue;
            size_t orow = (size_t)(base + row0 + m) * HD;
            for (int j = 0; j < 2; j++) {
                int n = n0 + wn * 32 + j * 16 + lr;
                float g = accg[i][j][r] + bg[e * HD + n];
                float u = accu[i][j][r] + bu[e * HD + n];
                float h = g * u / (1.f + __expf(-g));   // silu(g)*u
                Hbuf[orow + n] = (bf16)h;
            }
        }
    }
}

// gemm2: H2 = relu(Hbuf@W1 + b1). K=HD, NTY=8.  (proven 128^2 structure)
__global__ __launch_bounds__(256, 4) void k_gemm2(
    const bf16* __restrict__ Ain, const bf16* __restrict__ Bt, const float* __restrict__ bias,
    bf16* __restrict__ Out,
    const int* __restrict__ tileE, const int* __restrict__ tileR,
    const int* __restrict__ off, const int* __restrict__ ntp)
{
    __shared__ bf16 As[BM * BK];   // 16 KB
    __shared__ bf16 Bs[BN * BK];   // 16 KB
    DECODE_TILE(8, BN)
    f32x4 acc[4][4] = {};
    const bf16* Ab = Ain + (size_t)(base + row0) * HD;
    const bf16* Bb = Bt  + ((size_t)e * HD + n0) * HD;
    GEMM_KLOOP(HD)
    for (int i = 0; i < 4; i++) {
        int rb = wm * 64 + i * 16 + qd * 4;
        for (int r = 0; r < 4; r++) {
            int m = rb + r;
            if (m >= valid) continue;
            size_t orow = (size_t)(base + row0 + m) * HD;
            for (int j = 0; j < 4; j++) {
                int n = n0 + wn * 64 + j * 16 + lr;
                float v = acc[i][j][r] + bias[e * HD + n];
                Out[orow + n] = (bf16)(v > 0.f ? v : 0.f);
            }
        }
    }
}

// gemm3: out[perm] = H2@W2 + b2 (fp32 scatter). K=HD, NTY=2.
__global__ __launch_bounds__(256, 4) void k_gemm3(
    const bf16* __restrict__ Ain, const bf16* __restrict__ Bt, const float* __restrict__ bias,
    float* __restrict__ out, const int* __restrict__ perm,
    const int* __restrict__ tileE, const int* __restrict__ tileR,
    const int* __restrict__ off, const int* __restrict__ ntp)
{
    __shared__ bf16 As[BM * BK];
    __shared__ bf16 Bs[BN * BK];
    DECODE_TILE(2, BN)
    f32x4 acc[4][4] = {};
    const bf16* Ab = Ain + (size_t)(base + row0) * HD;
    const bf16* Bb = Bt  + ((size_t)e * OD + n0) * HD;
    GEMM_KLOOP(HD)
    for (int i = 0; i < 4; i++) {
        int rb = wm * 64 + i * 16 + qd * 4;
        for (int r = 0; r < 4; r++) {
            int m = rb + r;
            if (m >= valid) continue;
            int tok = perm[base + row0 + m];
            size_t orow = (size_t)tok * OD;
            for (int j = 0; j < 4; j++) {
                int n = n0 + wn * 64 + j * 16 + lr;
                out[orow + n] = acc[i][j][r] + bias[e * OD + n];
            }
        }
    }
}

// ---------------- launch ----------------
extern "C" void kernel_launch(void* const* d_in, const int* in_sizes, int n_in,
                              void* d_out, int out_size, void* d_ws, size_t ws_size,
                              hipStream_t stream) {
    const float* x   = (const float*)d_in[0];
    const int*   sel = (const int*)d_in[1];
    const float* Wg  = (const float*)d_in[2];
    const float* bg  = (const float*)d_in[3];
    const float* Wu  = (const float*)d_in[4];
    const float* bu  = (const float*)d_in[5];
    const float* W1  = (const float*)d_in[6];
    const float* b1  = (const float*)d_in[7];
    const float* W2  = (const float*)d_in[8];
    const float* b2  = (const float*)d_in[9];
    float* out = (float*)d_out;

    char* ws = (char*)d_ws;
    int* cnt    = (int*)(ws + O_CNT);
    int* cur    = (int*)(ws + O_CUR);
    int* off    = (int*)(ws + O_OFF);
    int* nt     = (int*)(ws + O_NT);
    int* nt2    = (int*)(ws + O_NT2);
    int* tileE  = (int*)(ws + O_TE);
    int* tileE2 = (int*)(ws + O_TE2);
    int* tileR  = (int*)(ws + O_TR);
    int* tileR2 = (int*)(ws + O_TR2);
    int* perm   = (int*)(ws + O_PERM);
    bf16* Xp    = (bf16*)(ws + O_XP);
    bf16* Wgt   = (bf16*)(ws + O_WG);
    bf16* Wut   = (bf16*)(ws + O_WU);
    bf16* W1t   = (bf16*)(ws + O_W1);
    bf16* W2t   = (bf16*)(ws + O_W2);
    bf16* Hbuf  = (bf16*)(ws + O_H);
    bf16* H2    = (bf16*)(ws + O_H2);

    hipMemsetAsync(ws, 0, 256, stream);

    k_hist   <<<NTOK / 256, 256, 0, stream>>>(sel, cnt);
    k_plan   <<<1, 64, 0, stream>>>(cnt, off, tileE, tileR, nt, tileE2, tileR2, nt2);
    k_scatter<<<NTOK / 256, 256, 0, stream>>>(sel, off, cur, perm);
    k_gather <<<NTOK * 64 / 256, 256, 0, stream>>>(x, perm, Xp);

    k_transpose_all<<<NEXP * TPE, 256, 0, stream>>>(Wg, Wgt, Wu, Wut, W1, W1t, W2, W2t);

    k_swiglu<<<RT8 * 16 * 8, 256, 0, stream>>>(Xp, Wgt, Wut, bg, bu, Hbuf,
                                               tileE, tileR, off, nt);
    k_gemm2 <<<RT8 * 8 * 8, 256, 0, stream>>>(Hbuf, W1t, b1, H2,
                                              tileE, tileR, off, nt);
    k_gemm3 <<<RT8 * 2 * 8, 256, 0, stream>>>(H2, W2t, b2, out, perm,
                                              tileE, tileR, off, nt);
}